// Round 4
// baseline (210.753 us; speedup 1.0000x reference)
//
#include <hip/hip_runtime.h>

// 2-level 2D Haar DWT, fused, one 4x16 input patch per thread (4 tiles).
// x: (96, 512, 512) fp32.
// History: persistent depth-1 (60.9us) == full-grid 58%-occ (60.0us) == +NT
// stores (59us) == 4x8 patch (60.2us). BUT round-3's VGPR_Count=28 proves the
// scheduler sank the "8 loads up-front" back into load->compute order: the
// per-wave-MLP experiment never ran. This version issues 16 independent 16B
// loads (16KB/wave) in tile order and pins them with sched_barrier(0) so they
// stay clustered; launch_bounds(256,3) gives the register budget (~170) to
// keep them all live. Consumption follows issue order -> progressive vmcnt
// drain; NT stores overlap the tail loads. Per-element arithmetic identical
// to reference (W first, then H, *KINV each stage).
// Out layout: a2,h2,v2,d2 (each 96*128*128), then h1,v1,d1 (each 96*256*256).

#define KINV 0.7071067811865476f

typedef float v4f __attribute__((ext_vector_type(4)));

__global__ __launch_bounds__(256, 3) void haar2_fused_kernel(
    const float* __restrict__ x, float* __restrict__ out, int nimg)
{
    const int tid = blockIdx.x * blockDim.x + threadIdx.x; // 0 .. nimg*4096-1
    const int cx  = tid & 31;           // 16-col patch index (lane-fast)
    const int r2  = (tid >> 5) & 127;   // level-2 row
    const int img = tid >> 12;          // 0..95

    const size_t n2 = (size_t)nimg * 128 * 128;
    const size_t n1 = (size_t)nimg * 256 * 256;
    float* a2o = out;
    float* h2o = out + n2;
    float* v2o = out + 2 * n2;
    float* d2o = out + 3 * n2;
    float* h1o = out + 4 * n2;
    float* v1o = h1o + n1;
    float* d1o = h1o + 2 * n1;

    const size_t in_base =
        (size_t)img * (512 * 512) + (size_t)(r2 * 4) * 512 + (size_t)cx * 16;

    // Issue ALL 16 loads, tile-major (tile t = cols 4t..4t+3), so consumption
    // order == issue order and vmcnt drains progressively.
    v4f b[4][4];   // b[t][k] = tile t, row k
    #pragma unroll
    for (int t = 0; t < 4; ++t)
        #pragma unroll
        for (int k = 0; k < 4; ++k)
            b[t][k] = *reinterpret_cast<const v4f*>(
                x + in_base + (size_t)k * 512 + (size_t)t * 4);

    // Hard fence: nothing may be scheduled across this point — the 16 loads
    // above must all be issued before any compute below.
    __builtin_amdgcn_sched_barrier(0);

    float a2v[4], h2v[4], v2v[4], d2v[4];
    float h1r[2][8], v1r[2][8], d1r[2][8];   // level-1 rows (2 rows x 8 cols)

    #pragma unroll
    for (int t = 0; t < 4; ++t) {
        float aa[2][2];
        #pragma unroll
        for (int i = 0; i < 2; ++i) {
            const v4f top = b[t][2 * i];
            const v4f bot = b[t][2 * i + 1];
            // cols 0,1 of tile — W-axis first, then H-axis (reference order)
            {
                const float sA = (top.x + top.y) * KINV;
                const float sB = (bot.x + bot.y) * KINV;
                const float dA = (top.x - top.y) * KINV;
                const float dB = (bot.x - bot.y) * KINV;
                aa[i][0]            = (sA + sB) * KINV;
                h1r[i][2 * t]       = (sA - sB) * KINV;   // cH1
                v1r[i][2 * t]       = (dA + dB) * KINV;   // cV1
                d1r[i][2 * t]       = (dA - dB) * KINV;   // cD1
            }
            // cols 2,3 of tile
            {
                const float sA = (top.z + top.w) * KINV;
                const float sB = (bot.z + bot.w) * KINV;
                const float dA = (top.z - top.w) * KINV;
                const float dB = (bot.z - bot.w) * KINV;
                aa[i][1]            = (sA + sB) * KINV;
                h1r[i][2 * t + 1]   = (sA - sB) * KINV;
                v1r[i][2 * t + 1]   = (dA + dB) * KINV;
                d1r[i][2 * t + 1]   = (dA - dB) * KINV;
            }
        }
        // Level 2 from this tile's aa quad.
        const float s0 = (aa[0][0] + aa[0][1]) * KINV;
        const float d0 = (aa[0][0] - aa[0][1]) * KINV;
        const float s1 = (aa[1][0] + aa[1][1]) * KINV;
        const float d1 = (aa[1][0] - aa[1][1]) * KINV;
        a2v[t] = (s0 + s1) * KINV;
        h2v[t] = (s0 - s1) * KINV;
        v2v[t] = (d0 + d1) * KINV;
        d2v[t] = (d0 - d1) * KINV;
    }

    // Level-1 detail stores: 2 x v4f per stream per row, adjacent addresses
    // (lanes 0..31 cover a contiguous 1KB row segment per instr pair). NT.
    const size_t img1 = (size_t)img * 256 * 256;
    #pragma unroll
    for (int i = 0; i < 2; ++i) {
        const size_t off = img1 + (size_t)(2 * r2 + i) * 256 + (size_t)cx * 8;
        #pragma unroll
        for (int h = 0; h < 2; ++h) {
            __builtin_nontemporal_store(
                (v4f){h1r[i][4*h], h1r[i][4*h+1], h1r[i][4*h+2], h1r[i][4*h+3]},
                reinterpret_cast<v4f*>(h1o + off + 4 * h));
            __builtin_nontemporal_store(
                (v4f){v1r[i][4*h], v1r[i][4*h+1], v1r[i][4*h+2], v1r[i][4*h+3]},
                reinterpret_cast<v4f*>(v1o + off + 4 * h));
            __builtin_nontemporal_store(
                (v4f){d1r[i][4*h], d1r[i][4*h+1], d1r[i][4*h+2], d1r[i][4*h+3]},
                reinterpret_cast<v4f*>(d1o + off + 4 * h));
        }
    }

    // Level-2 stores: one v4f per stream (lanes 0..31 -> contiguous 512B). NT.
    const size_t off2 = (size_t)img * 128 * 128 + (size_t)r2 * 128 + (size_t)cx * 4;
    __builtin_nontemporal_store((v4f){a2v[0], a2v[1], a2v[2], a2v[3]},
                                reinterpret_cast<v4f*>(a2o + off2));
    __builtin_nontemporal_store((v4f){h2v[0], h2v[1], h2v[2], h2v[3]},
                                reinterpret_cast<v4f*>(h2o + off2));
    __builtin_nontemporal_store((v4f){v2v[0], v2v[1], v2v[2], v2v[3]},
                                reinterpret_cast<v4f*>(v2o + off2));
    __builtin_nontemporal_store((v4f){d2v[0], d2v[1], d2v[2], d2v[3]},
                                reinterpret_cast<v4f*>(d2o + off2));
}

extern "C" void kernel_launch(void* const* d_in, const int* in_sizes, int n_in,
                              void* d_out, int out_size, void* d_ws, size_t ws_size,
                              hipStream_t stream) {
    const float* x = (const float*)d_in[0];
    float* out = (float*)d_out;
    const int nimg = in_sizes[0] / (512 * 512);   // 96
    const int total_threads = nimg * 128 * 32;    // 393,216 threads (4x16 patch each)
    const int block = 256;
    const int grid = total_threads / block;       // 1536 blocks (6/CU)
    haar2_fused_kernel<<<grid, block, 0, stream>>>(x, out, nimg);
}

// Round 5
// 176.465 us; speedup vs baseline: 1.1943x; 1.1943x over previous
//
#include <hip/hip_runtime.h>

// 2-level 2D Haar DWT, fused, LDS-staged via async global_load_lds.
// x: (96, 512, 512) fp32.
// History: 60us across persistent/full-grid/NT-store/4x8 variants; round-3/4
// attempts to deepen per-wave read MLP through registers were defeated by the
// VGPR allocator (VGPR_Count 28/56 < data size), and round-4's 32B-stride NT
// v4f stores inflated WRITE_SIZE 1.72x (partial 64B lines to HBM).
// This version: block = one contiguous 16-row stripe (32KB). Each wave issues
// 8 x 1KB __builtin_amdgcn_global_load_lds (16B/lane) for its own 4-row band
// -> 160KB of reads in flight per CU with ZERO register liveness (allocator
// can't serialize it). Then vmcnt(0), ds_read_b128 the 4x8 patch, identical
// arithmetic, round-2-proven store shapes (contiguous v4f/v2f, NT).
// Out layout: a2,h2,v2,d2 (each 96*128*128), then h1,v1,d1 (each 96*256*256).

#define KINV 0.7071067811865476f

typedef float v4f __attribute__((ext_vector_type(4)));
typedef float v2f __attribute__((ext_vector_type(2)));

#define STRIPE_ROWS 16
#define LDS_FLOATS (STRIPE_ROWS * 512)   // 8192 floats = 32 KB

__global__ __launch_bounds__(256) void haar2_fused_kernel(
    const float* __restrict__ x, float* __restrict__ out, int nimg)
{
    __shared__ float lds[LDS_FLOATS];

    const int tid  = threadIdx.x;
    const int lane = tid & 63;          // col-group within band
    const int w    = tid >> 6;          // wave id = 4-row band id (0..3)
    const int blk    = blockIdx.x;      // 0 .. nimg*32-1
    const int stripe = blk & 31;        // 16-row stripe within image
    const int img    = blk >> 5;

    const size_t n2 = (size_t)nimg * 128 * 128;
    const size_t n1 = (size_t)nimg * 256 * 256;
    float* a2o = out;
    float* h2o = out + n2;
    float* v2o = out + 2 * n2;
    float* d2o = out + 3 * n2;
    float* h1o = out + 4 * n2;
    float* v1o = h1o + n1;
    float* d1o = h1o + 2 * n1;

    const size_t stripe_base =
        (size_t)img * (512 * 512) + (size_t)stripe * (STRIPE_ROWS * 512);

    // ---- Async bulk copy: wave w copies its own 8KB band (rows 4w..4w+3) as
    // 8 x 1KB global_load_lds. LDS dest = wave-uniform base (+ lane*16B by HW);
    // global src = matching per-lane address. No VGPRs held, no barrier needed
    // (each wave consumes only its own band).
    {
        const float* gsrc = x + stripe_base + (size_t)(w * 2048) + (size_t)(lane * 4);
        float* ldst = &lds[w * 2048];
        #pragma unroll
        for (int j = 0; j < 8; ++j) {
            __builtin_amdgcn_global_load_lds(
                (const __attribute__((address_space(1))) void*)(gsrc + j * 256),
                (__attribute__((address_space(3))) void*)(ldst + j * 256),
                16, 0, 0);
        }
    }
    asm volatile("s_waitcnt vmcnt(0)" ::: "memory");
    __builtin_amdgcn_sched_barrier(0);

    // ---- Read back the 4x8 patch: rows 4w..4w+3, cols 8*lane..8*lane+7.
    const int cx = lane;
    v4f L[4], R[4];
    #pragma unroll
    for (int r = 0; r < 4; ++r) {
        const float* p = &lds[(w * 4 + r) * 512 + cx * 8];
        L[r] = *reinterpret_cast<const v4f*>(p);
        R[r] = *reinterpret_cast<const v4f*>(p + 4);
    }

    // ---- Level 1 (W-axis first, then H-axis, *KINV each stage — exact
    // reference op order). Two 4x4 tiles: L (cols 0..3), R (cols 4..7).
    float aaL[2][2], daL[2][2], adL[2][2], ddL[2][2];
    float aaR[2][2], daR[2][2], adR[2][2], ddR[2][2];
    #pragma unroll
    for (int i = 0; i < 2; ++i) {
        {
            const v4f top = L[2 * i], bot = L[2 * i + 1];
            const float sA0 = (top.x + top.y) * KINV, dA0 = (top.x - top.y) * KINV;
            const float sB0 = (bot.x + bot.y) * KINV, dB0 = (bot.x - bot.y) * KINV;
            aaL[i][0] = (sA0 + sB0) * KINV; daL[i][0] = (sA0 - sB0) * KINV;
            adL[i][0] = (dA0 + dB0) * KINV; ddL[i][0] = (dA0 - dB0) * KINV;
            const float sA1 = (top.z + top.w) * KINV, dA1 = (top.z - top.w) * KINV;
            const float sB1 = (bot.z + bot.w) * KINV, dB1 = (bot.z - bot.w) * KINV;
            aaL[i][1] = (sA1 + sB1) * KINV; daL[i][1] = (sA1 - sB1) * KINV;
            adL[i][1] = (dA1 + dB1) * KINV; ddL[i][1] = (dA1 - dB1) * KINV;
        }
        {
            const v4f top = R[2 * i], bot = R[2 * i + 1];
            const float sA0 = (top.x + top.y) * KINV, dA0 = (top.x - top.y) * KINV;
            const float sB0 = (bot.x + bot.y) * KINV, dB0 = (bot.x - bot.y) * KINV;
            aaR[i][0] = (sA0 + sB0) * KINV; daR[i][0] = (sA0 - sB0) * KINV;
            adR[i][0] = (dA0 + dB0) * KINV; ddR[i][0] = (dA0 - dB0) * KINV;
            const float sA1 = (top.z + top.w) * KINV, dA1 = (top.z - top.w) * KINV;
            const float sB1 = (bot.z + bot.w) * KINV, dB1 = (bot.z - bot.w) * KINV;
            aaR[i][1] = (sA1 + sB1) * KINV; daR[i][1] = (sA1 - sB1) * KINV;
            adR[i][1] = (dA1 + dB1) * KINV; ddR[i][1] = (dA1 - dB1) * KINV;
        }
    }

    // ---- Level-1 detail stores: v4f per stream per row, lanes at 16B stride
    // -> fully contiguous 1KB per instruction. NT (never re-read).
    const size_t img1 = (size_t)img * 256 * 256;
    const int l1row = stripe * 8 + w * 2;        // global level-1 row of i=0
    #pragma unroll
    for (int i = 0; i < 2; ++i) {
        const size_t off = img1 + (size_t)(l1row + i) * 256 + (size_t)cx * 4;
        __builtin_nontemporal_store((v4f){daL[i][0], daL[i][1], daR[i][0], daR[i][1]},
                                    reinterpret_cast<v4f*>(h1o + off));
        __builtin_nontemporal_store((v4f){adL[i][0], adL[i][1], adR[i][0], adR[i][1]},
                                    reinterpret_cast<v4f*>(v1o + off));
        __builtin_nontemporal_store((v4f){ddL[i][0], ddL[i][1], ddR[i][0], ddR[i][1]},
                                    reinterpret_cast<v4f*>(d1o + off));
    }

    // ---- Level 2 from the two aa quads (L -> col 2cx, R -> col 2cx+1).
    const float s0L = (aaL[0][0] + aaL[0][1]) * KINV;
    const float d0L = (aaL[0][0] - aaL[0][1]) * KINV;
    const float s1L = (aaL[1][0] + aaL[1][1]) * KINV;
    const float d1L = (aaL[1][0] - aaL[1][1]) * KINV;
    const float s0R = (aaR[0][0] + aaR[0][1]) * KINV;
    const float d0R = (aaR[0][0] - aaR[0][1]) * KINV;
    const float s1R = (aaR[1][0] + aaR[1][1]) * KINV;
    const float d1R = (aaR[1][0] - aaR[1][1]) * KINV;

    const size_t off2 = (size_t)img * (128 * 128)
                      + (size_t)(stripe * 4 + w) * 128 + (size_t)cx * 2;
    __builtin_nontemporal_store((v2f){(s0L + s1L) * KINV, (s0R + s1R) * KINV},
                                reinterpret_cast<v2f*>(a2o + off2));
    __builtin_nontemporal_store((v2f){(s0L - s1L) * KINV, (s0R - s1R) * KINV},
                                reinterpret_cast<v2f*>(h2o + off2));
    __builtin_nontemporal_store((v2f){(d0L + d1L) * KINV, (d0R + d1R) * KINV},
                                reinterpret_cast<v2f*>(v2o + off2));
    __builtin_nontemporal_store((v2f){(d0L - d1L) * KINV, (d0R - d1R) * KINV},
                                reinterpret_cast<v2f*>(d2o + off2));
}

extern "C" void kernel_launch(void* const* d_in, const int* in_sizes, int n_in,
                              void* d_out, int out_size, void* d_ws, size_t ws_size,
                              hipStream_t stream) {
    const float* x = (const float*)d_in[0];
    float* out = (float*)d_out;
    const int nimg = in_sizes[0] / (512 * 512);   // 96
    const int grid = nimg * 32;                   // 3072 blocks (16-row stripes)
    const int block = 256;
    haar2_fused_kernel<<<grid, block, 0, stream>>>(x, out, nimg);
}